// Round 19
// baseline (110.793 us; speedup 1.0000x reference)
//
#include <hip/hip_runtime.h>
#include <hip/hip_fp16.h>

static constexpr int NN   = 100000;
static constexpr int NE   = 2400000;
static constexpr int MSH  = 9;                     // mid bucket shift (512 nodes)
static constexpr unsigned MMSK = 511;
static constexpr int NND  = 512;                   // nodes per mid bucket
static constexpr int MBN  = (NN + 511) / 512;      // 196 mid buckets
static constexpr int CAPM = 13184;                 // per-mid capacity (mean 12245 + ~8.5 sigma)
static constexpr int NPB  = 1024;                  // partition blocks
static constexpr int SEG  = 2344;                  // edges per partition block (last ragged)
static_assert((size_t)NPB * SEG >= NE, "segments cover edge list");
static_assert(SEG % 4 == 0 && NE % 4 == 0 && CAPM % 4 == 0, "uint4 alignment");
static_assert(MBN <= 256, "mid hist fits one pass");
static_assert(NN % 32 == 0, "8-lane-per-node kernels assume NN % 32 == 0");

// init mid cursors (fixed-capacity bucket bases)
__global__ __launch_bounds__(256) void kinit(unsigned* __restrict__ cursor) {
    int i = threadIdx.x;
    if (i < MBN) cursor[i] = (unsigned)i * CAPM;
}

// fused hist + atomic space reservation + direct scatter into 196 mid regions.
// dst re-read is L1/L2-hot (9.4KB/segment). Open-line set unchanged vs r16-18.
__global__ __launch_bounds__(256) void kpartA(const int* __restrict__ src,
                                              const int* __restrict__ dst,
                                              unsigned* __restrict__ cursor,
                                              unsigned* __restrict__ csr) {
    __shared__ unsigned hist[MBN];
    __shared__ unsigned gb[MBN];
    int b = blockIdx.x, t = threadIdx.x;
    for (int k = t; k < MBN; k += 256) hist[k] = 0;
    __syncthreads();
    int off = b * SEG;
    int n = NE - off; if (n > SEG) n = SEG; if (n < 0) n = 0;
    for (int j = 4 * t; j + 3 < n; j += 1024) {
        uint4 d4 = *reinterpret_cast<const uint4*>(dst + off + j);
        atomicAdd(&hist[d4.x >> MSH], 1u);
        atomicAdd(&hist[d4.y >> MSH], 1u);
        atomicAdd(&hist[d4.z >> MSH], 1u);
        atomicAdd(&hist[d4.w >> MSH], 1u);
    }
    __syncthreads();
    if (t < MBN) {
        unsigned c = hist[t];
        gb[t] = c ? atomicAdd(&cursor[t], c) : 0u;   // reserve contiguous run
    }
    __syncthreads();
    if (t < MBN) hist[t] = 0;          // reuse as local run offset
    __syncthreads();
    for (int j = 4 * t; j + 3 < n; j += 1024) {
        uint4 d4 = *reinterpret_cast<const uint4*>(dst + off + j);
        uint4 s4 = *reinterpret_cast<const uint4*>(src + off + j);
        unsigned k0 = d4.x >> MSH;
        csr[gb[k0] + atomicAdd(&hist[k0], 1u)] = (s4.x << MSH) | (d4.x & MMSK);
        unsigned k1 = d4.y >> MSH;
        csr[gb[k1] + atomicAdd(&hist[k1], 1u)] = (s4.y << MSH) | (d4.y & MMSK);
        unsigned k2 = d4.z >> MSH;
        csr[gb[k2] + atomicAdd(&hist[k2], 1u)] = (s4.z << MSH) | (d4.z & MMSK);
        unsigned k3 = d4.w >> MSH;
        csr[gb[k3] + atomicAdd(&hist[k3], 1u)] = (s4.w << MSH) | (d4.w & MMSK);
    }
}

// single-pass mid->node sort: one block (512 threads) per mid bucket.
__global__ __launch_bounds__(512) void kcsrB2(const unsigned* __restrict__ csr,
                                              const unsigned* __restrict__ cursor,
                                              const float* __restrict__ x,
                                              unsigned* __restrict__ csr2,
                                              unsigned* __restrict__ rstart,
                                              unsigned* __restrict__ rcnt,
                                              float* __restrict__ dis,
                                              float* __restrict__ y1) {
    __shared__ __align__(16) unsigned codes[CAPM];   // 52.7 KB
    __shared__ int cnt[NND];
    __shared__ unsigned ps1[NND], ps2[NND];
    __shared__ unsigned cur[NND];
    int m = blockIdx.x, t = threadIdx.x;
    unsigned sbase = (unsigned)m * CAPM;
    unsigned nM = cursor[m] - sbase; if (nM > CAPM) nM = CAPM;
    cnt[t] = 0;
    __syncthreads();
    unsigned nM4 = nM & ~3u;
    for (unsigned j = 4u * t; j < nM4; j += 2048) {
        uint4 c4 = *reinterpret_cast<const uint4*>(csr + sbase + j);
        *reinterpret_cast<uint4*>(&codes[j]) = c4;
        atomicAdd(&cnt[c4.x & MMSK], 1);
        atomicAdd(&cnt[c4.y & MMSK], 1);
        atomicAdd(&cnt[c4.z & MMSK], 1);
        atomicAdd(&cnt[c4.w & MMSK], 1);
    }
    for (unsigned j = nM4 + t; j < nM; j += 512) {
        unsigned c = csr[sbase + j];
        codes[j] = c;
        atomicAdd(&cnt[c & MMSK], 1);
    }
    __syncthreads();
    // 512-wide Hillis-Steele exclusive scan (one count per thread)
    unsigned v = (unsigned)cnt[t];
    ps1[t] = v;
    __syncthreads();
    unsigned* cu = ps1; unsigned* nx = ps2;
    for (int o = 1; o < 512; o <<= 1) {
        unsigned s = cu[t];
        if (t >= o) s += cu[t - o];
        nx[t] = s;
        __syncthreads();
        unsigned* tm = cu; cu = nx; nx = tm;
    }
    unsigned excl = cu[t] - v;
    cur[t] = excl;
    int node = m * NND + t;
    if (node < NN) {
        rstart[node] = sbase + excl;
        rcnt[node] = v;
        float d = rsqrtf((float)((int)v + 1));
        dis[node] = d;
        y1[node] = d * x[node];
    }
    __syncthreads();
    // scatter from LDS to global (49KB window per block -> L2 open-line safe)
    for (unsigned j = t; j < nM; j += 512) {
        unsigned c = codes[j];
        unsigned pos = atomicAdd(&cur[c & MMSK], 1u);
        csr2[sbase + pos] = c >> MSH;      // src node id, grouped by dst node
    }
}

// ---- aggregation phase ----

// layer-1 aggregate (8 lanes/node) + dense 1->32->16; lane l emits features
// {2l,2l+1} as one coalesced __half2 (y2 fp16, 3.2MB -> L2-resident)
__global__ __launch_bounds__(256) void kagg1lin(const unsigned* __restrict__ srcs,
                                                const unsigned* __restrict__ rstart,
                                                const unsigned* __restrict__ rcnt,
                                                const float* __restrict__ y1,
                                                const float* __restrict__ dis,
                                                const float* __restrict__ W1,
                                                const float* __restrict__ b1,
                                                const float* __restrict__ W2,
                                                __half2* __restrict__ y2) {
    __shared__ float sW1[32], sb1[32], sW2[512];
    int t = threadIdx.x;
    if (t < 32) { sW1[t] = W1[t]; sb1[t] = b1[t]; }
    for (int i = t; i < 512; i += 256) sW2[i] = W2[i];
    __syncthreads();
    int node = blockIdx.x * 32 + (t >> 3);
    int l = t & 7;
    unsigned r0 = rstart[node], r1 = r0 + rcnt[node];
    float s0 = 0.f, s1 = 0.f;
    unsigned j = r0 + l;
    for (; j + 8 < r1; j += 16) {
        unsigned i0 = srcs[j], i1 = srcs[j + 8];
        float v0 = y1[i0], v1 = y1[i1];
        s0 += v0; s1 += v1;
    }
    if (j < r1) s0 += y1[srcs[j]];
    float sum = s0 + s1;
    sum += __shfl_xor(sum, 1, 8);
    sum += __shfl_xor(sum, 2, 8);
    sum += __shfl_xor(sum, 4, 8);           // all 8 lanes hold the total
    float d = dis[node];
    float a = d * (sum + y1[node]);
    float acc0 = 0.f, acc1 = 0.f;
#pragma unroll
    for (int f = 0; f < 32; ++f) {
        float h = fmaxf(a * sW1[f] + sb1[f], 0.f);
        acc0 += h * sW2[f * 16 + 2 * l];
        acc1 += h * sW2[f * 16 + 2 * l + 1];
    }
    y2[(size_t)node * 8 + l] = __floats2half2_rn(d * acc0, d * acc1);
}

// 16-wide gather aggregate fused with layer-3 linear. 8 lanes per node,
// __half2 loads: one gather instruction services 8 edges.
__global__ __launch_bounds__(256) void kagg16g(const unsigned* __restrict__ srcs,
                                               const unsigned* __restrict__ rstart,
                                               const unsigned* __restrict__ rcnt,
                                               const __half2* __restrict__ y2,
                                               const float* __restrict__ dis,
                                               const float* __restrict__ b2,
                                               const float* __restrict__ W3,
                                               float* __restrict__ y3) {
    int t = threadIdx.x;
    int node = blockIdx.x * 32 + (t >> 3);
    int l = t & 7;
    unsigned r0 = rstart[node], r1 = r0 + rcnt[node];
    const __half2* yl = y2 + l;            // row i at y2[i*8 + l]
    float sx0 = 0.f, sy0 = 0.f, sx1 = 0.f, sy1 = 0.f;
    float sx2 = 0.f, sy2 = 0.f, sx3 = 0.f, sy3 = 0.f;
    unsigned j = r0;
    for (; j + 8 <= r1; j += 8) {
        unsigned i0 = srcs[j + 0], i1 = srcs[j + 1], i2 = srcs[j + 2], i3 = srcs[j + 3];
        unsigned i4 = srcs[j + 4], i5 = srcs[j + 5], i6 = srcs[j + 6], i7 = srcs[j + 7];
        float2 v0 = __half22float2(yl[(size_t)i0 * 8]);
        float2 v1 = __half22float2(yl[(size_t)i1 * 8]);
        float2 v2 = __half22float2(yl[(size_t)i2 * 8]);
        float2 v3 = __half22float2(yl[(size_t)i3 * 8]);
        float2 v4 = __half22float2(yl[(size_t)i4 * 8]);
        float2 v5 = __half22float2(yl[(size_t)i5 * 8]);
        float2 v6 = __half22float2(yl[(size_t)i6 * 8]);
        float2 v7 = __half22float2(yl[(size_t)i7 * 8]);
        sx0 += v0.x; sy0 += v0.y; sx1 += v1.x; sy1 += v1.y;
        sx2 += v2.x; sy2 += v2.y; sx3 += v3.x; sy3 += v3.y;
        sx0 += v4.x; sy0 += v4.y; sx1 += v5.x; sy1 += v5.y;
        sx2 += v6.x; sy2 += v6.y; sx3 += v7.x; sy3 += v7.y;
    }
    for (; j + 2 <= r1; j += 2) {
        unsigned i0 = srcs[j], i1 = srcs[j + 1];
        float2 v0 = __half22float2(yl[(size_t)i0 * 8]);
        float2 v1 = __half22float2(yl[(size_t)i1 * 8]);
        sx0 += v0.x; sy0 += v0.y; sx1 += v1.x; sy1 += v1.y;
    }
    if (j < r1) {
        float2 v = __half22float2(yl[(size_t)srcs[j] * 8]);
        sx2 += v.x; sy2 += v.y;
    }
    float sumx = (sx0 + sx1) + (sx2 + sx3);
    float sumy = (sy0 + sy1) + (sy2 + sy3);
    float d = dis[node];
    float2 self = __half22float2(yl[(size_t)node * 8]);
    float ax = d * (sumx + self.x) + b2[2 * l];
    float ay = d * (sumy + self.y) + b2[2 * l + 1];
    float hg = fmaxf(ax, 0.f) * W3[2 * l] + fmaxf(ay, 0.f) * W3[2 * l + 1];
    hg += __shfl_xor(hg, 1, 8);
    hg += __shfl_xor(hg, 2, 8);
    hg += __shfl_xor(hg, 4, 8);
    if (l == 0) y3[node] = d * hg;
}

// scalar gather aggregate: 8 lanes per node
__global__ __launch_bounds__(256) void kaggsg(const unsigned* __restrict__ srcs,
                                              const unsigned* __restrict__ rstart,
                                              const unsigned* __restrict__ rcnt,
                                              const float* __restrict__ y,
                                              const float* __restrict__ dis,
                                              float* __restrict__ out,
                                              const float* __restrict__ bias) {
    int t = threadIdx.x;
    int node = blockIdx.x * 32 + (t >> 3);
    int l = t & 7;
    unsigned r0 = rstart[node], r1 = r0 + rcnt[node];
    float s0 = 0.f, s1 = 0.f;
    unsigned j = r0 + l;
    for (; j + 8 < r1; j += 16) {
        unsigned i0 = srcs[j], i1 = srcs[j + 8];
        float v0 = y[i0], v1 = y[i1];
        s0 += v0; s1 += v1;
    }
    if (j < r1) s0 += y[srcs[j]];
    float sum = s0 + s1;
    sum += __shfl_xor(sum, 1, 8);
    sum += __shfl_xor(sum, 2, 8);
    sum += __shfl_xor(sum, 4, 8);
    if (l == 0) {
        float d = dis[node];
        out[node] = d * (sum + y[node]) + (bias ? bias[0] : 0.f);
    }
}

extern "C" void kernel_launch(void* const* d_in, const int* in_sizes, int n_in,
                              void* d_out, int out_size, void* d_ws, size_t ws_size,
                              hipStream_t stream) {
    const float* x  = (const float*)d_in[0];
    const int*   ei = (const int*)d_in[1];
    const int* src = ei;
    const int* dst = ei + NE;
    const float* W1 = (const float*)d_in[2];
    const float* b1 = (const float*)d_in[3];
    const float* W2 = (const float*)d_in[4];
    const float* b2 = (const float*)d_in[5];
    const float* W3 = (const float*)d_in[6];
    const float* b3 = (const float*)d_in[7];
    float* out = (float*)d_out;

    auto align256 = [](size_t v) { return (v + 255) & ~(size_t)255; };
    char* w = (char*)d_ws;
    auto carve = [&](size_t bytes) { char* p = w; w += align256(bytes); return p; };

    // region A: mid-bucket code regions (dead after kcsrB2) -> reused as fp16 y2
    char* regA = carve((size_t)MBN * CAPM * 4);                 // 10.3 MB
    unsigned* csr = (unsigned*)regA;
    __half2*  y2  = (__half2*)regA;                             // 3.2 MB used
    unsigned* csr2   = (unsigned*)carve((size_t)MBN * CAPM * 4);// 10.3 MB
    unsigned* cursor = (unsigned*)carve((size_t)MBN * 4);
    unsigned* rstart = (unsigned*)carve((size_t)NN * 4);
    unsigned* rcnt   = (unsigned*)carve((size_t)NN * 4);
    float*    dis    = (float*)   carve((size_t)NN * 4);
    float*    y1     = (float*)   carve((size_t)NN * 4);
    float*    y3     = (float*)   carve((size_t)NN * 4);

    dim3 B(256);

    // partition: cursor init -> fused hist/reserve/scatter -> node sort
    kinit <<<1, B, 0, stream>>>(cursor);
    kpartA<<<NPB, B, 0, stream>>>(src, dst, cursor, csr);
    kcsrB2<<<MBN, dim3(512), 0, stream>>>(csr, cursor, x, csr2, rstart, rcnt, dis, y1);

    // layer 1 aggregate (8-lane) + dense 1->32->16 -> y2 (fp16) = dis*h2pre
    kagg1lin<<<NN / 32, B, 0, stream>>>(csr2, rstart, rcnt, y1, dis, W1, b1, W2, y2);

    // layer 2 aggregate (8-lane half2 gathers, L2-resident) + layer-3 linear -> y3
    kagg16g <<<NN / 32, B, 0, stream>>>(csr2, rstart, rcnt, y2, dis, b2, W3, y3);

    // layer 3 aggregate (8-lane scalar) -> out
    kaggsg  <<<NN / 32, B, 0, stream>>>(csr2, rstart, rcnt, y3, dis, out, b3);
}

// Round 20
// 96.933 us; speedup vs baseline: 1.1430x; 1.1430x over previous
//
#include <hip/hip_runtime.h>
#include <hip/hip_fp16.h>

static constexpr int NN   = 100000;
static constexpr int NE   = 2400000;
static constexpr int MSH  = 9;                     // mid bucket shift (512 nodes)
static constexpr unsigned MMSK = 511;
static constexpr int NND  = 512;                   // nodes per mid bucket
static constexpr int MBN  = (NN + 511) / 512;      // 196 mid buckets
static constexpr int CAPM = 13184;                 // per-mid capacity (mean 12245 + ~8.5 sigma)
static constexpr int NPB  = 1024;                  // partition blocks
static constexpr int SEG  = 2344;                  // edges per partition block (last ragged)
static_assert((size_t)NPB * SEG >= NE, "segments cover edge list");
static_assert(SEG % 4 == 0 && NE % 4 == 0 && CAPM % 4 == 0, "uint4 alignment");
static_assert(MBN <= 256, "mid hist fits one pass");
static_assert(NN % 32 == 0, "8-lane-per-node kernels assume NN % 32 == 0");

// per-segment histogram over 196 mid buckets -> H[block][mid]; uint4 loads
__global__ __launch_bounds__(256) void khistM(const int* __restrict__ dst,
                                              unsigned* __restrict__ H) {
    __shared__ unsigned h[MBN];
    int b = blockIdx.x, t = threadIdx.x;
    for (int k = t; k < MBN; k += 256) h[k] = 0;
    __syncthreads();
    int off = b * SEG;
    int n = NE - off; if (n > SEG) n = SEG; if (n < 0) n = 0;
    for (int j = 4 * t; j + 3 < n; j += 1024) {
        uint4 d4 = *reinterpret_cast<const uint4*>(dst + off + j);
        atomicAdd(&h[d4.x >> MSH], 1u);
        atomicAdd(&h[d4.y >> MSH], 1u);
        atomicAdd(&h[d4.z >> MSH], 1u);
        atomicAdd(&h[d4.w >> MSH], 1u);
    }
    __syncthreads();
    for (int k = t; k < MBN; k += 256) H[(size_t)b * MBN + k] = h[k];
}

// per-mid exclusive scan over the 1024 blocks -> P[mid][block]
__global__ __launch_bounds__(1024) void kscanM(const unsigned* __restrict__ H,
                                               unsigned* __restrict__ P,
                                               unsigned* __restrict__ cntM) {
    __shared__ unsigned a[1024], b2[1024];
    int k = blockIdx.x, t = threadIdx.x;
    unsigned v = H[(size_t)t * MBN + k];   // strided read, H is L2-resident
    a[t] = v;
    __syncthreads();
    unsigned* cu = a; unsigned* nx = b2;
    for (int o = 1; o < 1024; o <<= 1) {
        unsigned x = cu[t];
        if (t >= o) x += cu[t - o];
        nx[t] = x;
        __syncthreads();
        unsigned* tm = cu; cu = nx; nx = tm;
    }
    P[(size_t)k * NPB + t] = cu[t] - v;
    if (t == 1023) cntM[k] = cu[t];
}

// direct scatter into 196 fixed-capacity mid regions; uint4 streaming loads.
// Open-line set: 128 blocks/XCD * 196 lines * 64B = 1.6MB < 4MB L2.
__global__ __launch_bounds__(256) void kscatterM(const int* __restrict__ src,
                                                 const int* __restrict__ dst,
                                                 const unsigned* __restrict__ P,
                                                 unsigned* __restrict__ csr) {
    __shared__ unsigned lcur[MBN];
    int b = blockIdx.x, t = threadIdx.x;
    for (int k = t; k < MBN; k += 256)
        lcur[k] = (unsigned)k * CAPM + P[(size_t)k * NPB + b];
    __syncthreads();
    int off = b * SEG;
    int n = NE - off; if (n > SEG) n = SEG; if (n < 0) n = 0;
    for (int j = 4 * t; j + 3 < n; j += 1024) {
        uint4 d4 = *reinterpret_cast<const uint4*>(dst + off + j);
        uint4 s4 = *reinterpret_cast<const uint4*>(src + off + j);
        unsigned p0 = atomicAdd(&lcur[d4.x >> MSH], 1u);
        csr[p0] = (s4.x << MSH) | (d4.x & MMSK);
        unsigned p1 = atomicAdd(&lcur[d4.y >> MSH], 1u);
        csr[p1] = (s4.y << MSH) | (d4.y & MMSK);
        unsigned p2 = atomicAdd(&lcur[d4.z >> MSH], 1u);
        csr[p2] = (s4.z << MSH) | (d4.z & MMSK);
        unsigned p3 = atomicAdd(&lcur[d4.w >> MSH], 1u);
        csr[p3] = (s4.w << MSH) | (d4.w & MMSK);
    }
}

// single-pass mid->node sort: one block (512 threads) per mid bucket.
__global__ __launch_bounds__(512) void kcsrB2(const unsigned* __restrict__ csr,
                                              const unsigned* __restrict__ cntM,
                                              const float* __restrict__ x,
                                              unsigned* __restrict__ csr2,
                                              unsigned* __restrict__ rstart,
                                              unsigned* __restrict__ rcnt,
                                              float* __restrict__ dis,
                                              float* __restrict__ y1) {
    __shared__ __align__(16) unsigned codes[CAPM];   // 52.7 KB
    __shared__ int cnt[NND];
    __shared__ unsigned ps1[NND], ps2[NND];
    __shared__ unsigned cur[NND];
    int m = blockIdx.x, t = threadIdx.x;
    unsigned sbase = (unsigned)m * CAPM;
    unsigned nM = cntM[m]; if (nM > CAPM) nM = CAPM;
    cnt[t] = 0;
    __syncthreads();
    unsigned nM4 = nM & ~3u;
    for (unsigned j = 4u * t; j < nM4; j += 2048) {
        uint4 c4 = *reinterpret_cast<const uint4*>(csr + sbase + j);
        *reinterpret_cast<uint4*>(&codes[j]) = c4;
        atomicAdd(&cnt[c4.x & MMSK], 1);
        atomicAdd(&cnt[c4.y & MMSK], 1);
        atomicAdd(&cnt[c4.z & MMSK], 1);
        atomicAdd(&cnt[c4.w & MMSK], 1);
    }
    for (unsigned j = nM4 + t; j < nM; j += 512) {
        unsigned c = csr[sbase + j];
        codes[j] = c;
        atomicAdd(&cnt[c & MMSK], 1);
    }
    __syncthreads();
    // 512-wide Hillis-Steele exclusive scan (one count per thread)
    unsigned v = (unsigned)cnt[t];
    ps1[t] = v;
    __syncthreads();
    unsigned* cu = ps1; unsigned* nx = ps2;
    for (int o = 1; o < 512; o <<= 1) {
        unsigned s = cu[t];
        if (t >= o) s += cu[t - o];
        nx[t] = s;
        __syncthreads();
        unsigned* tm = cu; cu = nx; nx = tm;
    }
    unsigned excl = cu[t] - v;
    cur[t] = excl;
    int node = m * NND + t;
    if (node < NN) {
        rstart[node] = sbase + excl;
        rcnt[node] = v;
        float d = rsqrtf((float)((int)v + 1));
        dis[node] = d;
        y1[node] = d * x[node];
    }
    __syncthreads();
    // scatter from LDS to global (49KB window per block -> L2 open-line safe)
    for (unsigned j = t; j < nM; j += 512) {
        unsigned c = codes[j];
        unsigned pos = atomicAdd(&cur[c & MMSK], 1u);
        csr2[sbase + pos] = c >> MSH;      // src node id, grouped by dst node
    }
}

// ---- aggregation phase ----

// layer-1 aggregate (8 lanes/node) + dense 1->32->16; lane l emits features
// {2l,2l+1} as one coalesced __half2 (y2 fp16, 3.2MB -> L2-resident)
__global__ __launch_bounds__(256) void kagg1lin(const unsigned* __restrict__ srcs,
                                                const unsigned* __restrict__ rstart,
                                                const unsigned* __restrict__ rcnt,
                                                const float* __restrict__ y1,
                                                const float* __restrict__ dis,
                                                const float* __restrict__ W1,
                                                const float* __restrict__ b1,
                                                const float* __restrict__ W2,
                                                __half2* __restrict__ y2) {
    __shared__ float sW1[32], sb1[32], sW2[512];
    int t = threadIdx.x;
    if (t < 32) { sW1[t] = W1[t]; sb1[t] = b1[t]; }
    for (int i = t; i < 512; i += 256) sW2[i] = W2[i];
    __syncthreads();
    int node = blockIdx.x * 32 + (t >> 3);
    int l = t & 7;
    unsigned r0 = rstart[node], r1 = r0 + rcnt[node];
    float s0 = 0.f, s1 = 0.f;
    unsigned j = r0 + l;
    for (; j + 8 < r1; j += 16) {
        unsigned i0 = srcs[j], i1 = srcs[j + 8];
        float v0 = y1[i0], v1 = y1[i1];
        s0 += v0; s1 += v1;
    }
    if (j < r1) s0 += y1[srcs[j]];
    float sum = s0 + s1;
    sum += __shfl_xor(sum, 1, 8);
    sum += __shfl_xor(sum, 2, 8);
    sum += __shfl_xor(sum, 4, 8);           // all 8 lanes hold the total
    float d = dis[node];
    float a = d * (sum + y1[node]);
    float acc0 = 0.f, acc1 = 0.f;
#pragma unroll
    for (int f = 0; f < 32; ++f) {
        float h = fmaxf(a * sW1[f] + sb1[f], 0.f);
        acc0 += h * sW2[f * 16 + 2 * l];
        acc1 += h * sW2[f * 16 + 2 * l + 1];
    }
    y2[(size_t)node * 8 + l] = __floats2half2_rn(d * acc0, d * acc1);
}

// 16-wide gather aggregate fused with layer-3 linear. 8 lanes per node,
// __half2 loads: one gather instruction services 8 edges.
__global__ __launch_bounds__(256) void kagg16g(const unsigned* __restrict__ srcs,
                                               const unsigned* __restrict__ rstart,
                                               const unsigned* __restrict__ rcnt,
                                               const __half2* __restrict__ y2,
                                               const float* __restrict__ dis,
                                               const float* __restrict__ b2,
                                               const float* __restrict__ W3,
                                               float* __restrict__ y3) {
    int t = threadIdx.x;
    int node = blockIdx.x * 32 + (t >> 3);
    int l = t & 7;
    unsigned r0 = rstart[node], r1 = r0 + rcnt[node];
    const __half2* yl = y2 + l;            // row i at y2[i*8 + l]
    float sx0 = 0.f, sy0 = 0.f, sx1 = 0.f, sy1 = 0.f;
    float sx2 = 0.f, sy2 = 0.f, sx3 = 0.f, sy3 = 0.f;
    unsigned j = r0;
    for (; j + 8 <= r1; j += 8) {
        unsigned i0 = srcs[j + 0], i1 = srcs[j + 1], i2 = srcs[j + 2], i3 = srcs[j + 3];
        unsigned i4 = srcs[j + 4], i5 = srcs[j + 5], i6 = srcs[j + 6], i7 = srcs[j + 7];
        float2 v0 = __half22float2(yl[(size_t)i0 * 8]);
        float2 v1 = __half22float2(yl[(size_t)i1 * 8]);
        float2 v2 = __half22float2(yl[(size_t)i2 * 8]);
        float2 v3 = __half22float2(yl[(size_t)i3 * 8]);
        float2 v4 = __half22float2(yl[(size_t)i4 * 8]);
        float2 v5 = __half22float2(yl[(size_t)i5 * 8]);
        float2 v6 = __half22float2(yl[(size_t)i6 * 8]);
        float2 v7 = __half22float2(yl[(size_t)i7 * 8]);
        sx0 += v0.x; sy0 += v0.y; sx1 += v1.x; sy1 += v1.y;
        sx2 += v2.x; sy2 += v2.y; sx3 += v3.x; sy3 += v3.y;
        sx0 += v4.x; sy0 += v4.y; sx1 += v5.x; sy1 += v5.y;
        sx2 += v6.x; sy2 += v6.y; sx3 += v7.x; sy3 += v7.y;
    }
    for (; j + 2 <= r1; j += 2) {
        unsigned i0 = srcs[j], i1 = srcs[j + 1];
        float2 v0 = __half22float2(yl[(size_t)i0 * 8]);
        float2 v1 = __half22float2(yl[(size_t)i1 * 8]);
        sx0 += v0.x; sy0 += v0.y; sx1 += v1.x; sy1 += v1.y;
    }
    if (j < r1) {
        float2 v = __half22float2(yl[(size_t)srcs[j] * 8]);
        sx2 += v.x; sy2 += v.y;
    }
    float sumx = (sx0 + sx1) + (sx2 + sx3);
    float sumy = (sy0 + sy1) + (sy2 + sy3);
    float d = dis[node];
    float2 self = __half22float2(yl[(size_t)node * 8]);
    float ax = d * (sumx + self.x) + b2[2 * l];
    float ay = d * (sumy + self.y) + b2[2 * l + 1];
    float hg = fmaxf(ax, 0.f) * W3[2 * l] + fmaxf(ay, 0.f) * W3[2 * l + 1];
    hg += __shfl_xor(hg, 1, 8);
    hg += __shfl_xor(hg, 2, 8);
    hg += __shfl_xor(hg, 4, 8);
    if (l == 0) y3[node] = d * hg;
}

// scalar gather aggregate: 8 lanes per node
__global__ __launch_bounds__(256) void kaggsg(const unsigned* __restrict__ srcs,
                                              const unsigned* __restrict__ rstart,
                                              const unsigned* __restrict__ rcnt,
                                              const float* __restrict__ y,
                                              const float* __restrict__ dis,
                                              float* __restrict__ out,
                                              const float* __restrict__ bias) {
    int t = threadIdx.x;
    int node = blockIdx.x * 32 + (t >> 3);
    int l = t & 7;
    unsigned r0 = rstart[node], r1 = r0 + rcnt[node];
    float s0 = 0.f, s1 = 0.f;
    unsigned j = r0 + l;
    for (; j + 8 < r1; j += 16) {
        unsigned i0 = srcs[j], i1 = srcs[j + 8];
        float v0 = y[i0], v1 = y[i1];
        s0 += v0; s1 += v1;
    }
    if (j < r1) s0 += y[srcs[j]];
    float sum = s0 + s1;
    sum += __shfl_xor(sum, 1, 8);
    sum += __shfl_xor(sum, 2, 8);
    sum += __shfl_xor(sum, 4, 8);
    if (l == 0) {
        float d = dis[node];
        out[node] = d * (sum + y[node]) + (bias ? bias[0] : 0.f);
    }
}

extern "C" void kernel_launch(void* const* d_in, const int* in_sizes, int n_in,
                              void* d_out, int out_size, void* d_ws, size_t ws_size,
                              hipStream_t stream) {
    const float* x  = (const float*)d_in[0];
    const int*   ei = (const int*)d_in[1];
    const int* src = ei;
    const int* dst = ei + NE;
    const float* W1 = (const float*)d_in[2];
    const float* b1 = (const float*)d_in[3];
    const float* W2 = (const float*)d_in[4];
    const float* b2 = (const float*)d_in[5];
    const float* W3 = (const float*)d_in[6];
    const float* b3 = (const float*)d_in[7];
    float* out = (float*)d_out;

    auto align256 = [](size_t v) { return (v + 255) & ~(size_t)255; };
    char* w = (char*)d_ws;
    auto carve = [&](size_t bytes) { char* p = w; w += align256(bytes); return p; };

    // region A: mid-bucket code regions (dead after kcsrB2) -> reused as fp16 y2
    char* regA = carve((size_t)MBN * CAPM * 4);                 // 10.3 MB
    unsigned* csr = (unsigned*)regA;
    __half2*  y2  = (__half2*)regA;                             // 3.2 MB used
    unsigned* csr2   = (unsigned*)carve((size_t)MBN * CAPM * 4);// 10.3 MB
    unsigned* H      = (unsigned*)carve((size_t)NPB * MBN * 4); // 800 KB
    unsigned* P      = (unsigned*)carve((size_t)MBN * NPB * 4); // 800 KB
    unsigned* cntM   = (unsigned*)carve((size_t)MBN * 4);
    unsigned* rstart = (unsigned*)carve((size_t)NN * 4);
    unsigned* rcnt   = (unsigned*)carve((size_t)NN * 4);
    float*    dis    = (float*)   carve((size_t)NN * 4);
    float*    y1     = (float*)   carve((size_t)NN * 4);
    float*    y3     = (float*)   carve((size_t)NN * 4);

    dim3 B(256);

    // partition: mid hist -> deterministic P scan -> direct mid scatter -> node sort
    khistM   <<<NPB, B, 0, stream>>>(dst, H);
    kscanM   <<<MBN, dim3(1024), 0, stream>>>(H, P, cntM);
    kscatterM<<<NPB, B, 0, stream>>>(src, dst, P, csr);
    kcsrB2   <<<MBN, dim3(512), 0, stream>>>(csr, cntM, x, csr2, rstart, rcnt, dis, y1);

    // layer 1 aggregate (8-lane) + dense 1->32->16 -> y2 (fp16) = dis*h2pre
    kagg1lin<<<NN / 32, B, 0, stream>>>(csr2, rstart, rcnt, y1, dis, W1, b1, W2, y2);

    // layer 2 aggregate (8-lane half2 gathers, L2-resident) + layer-3 linear -> y3
    kagg16g <<<NN / 32, B, 0, stream>>>(csr2, rstart, rcnt, y2, dis, b2, W3, y3);

    // layer 3 aggregate (8-lane scalar) -> out
    kaggsg  <<<NN / 32, B, 0, stream>>>(csr2, rstart, rcnt, y3, dis, out, b3);
}